// Round 1
// baseline (1456.113 us; speedup 1.0000x reference)
//
#include <hip/hip_runtime.h>
#include <math.h>

#define NRAYS 8192
#define NPP   24      // samples per ray
#define CP    32      // channels per plane
#define RES   256     // plane resolution
#define WH    256     // hidden width
#define INDIM 96      // 3*CP
#define VD    27      // viewdir encoding dim

// output chunk offsets (flat f32)
#define RGB_OFF  0
#define FEAT_OFF 24576
#define SDF_OFF  2121728
#define MASK_OFF 2318336
#define XYZ_OFF  2326528

__device__ __forceinline__ float softplusf(float x) {
    // matches jax.nn.softplus: max(x,0) + log1p(exp(-|x|))
    return fmaxf(x, 0.0f) + log1pf(expf(-fabsf(x)));
}
__device__ __forceinline__ float sigmoidf_(float x) {
    return 1.0f / (1.0f + expf(-x));
}

__global__ void triplane_fused(
    const float* __restrict__ planes, const float* __restrict__ pts,
    const float* __restrict__ rays_d, const float* __restrict__ viewdirs,
    const float* __restrict__ z_vals, const float* __restrict__ nearp,
    const float* __restrict__ farp,
    const float* __restrict__ w_sig0, const float* __restrict__ b_sig0,
    const float* __restrict__ w_sig1, const float* __restrict__ b_sig1,
    const float* __restrict__ w_v0,  const float* __restrict__ b_v0,
    const float* __restrict__ w_v1,  const float* __restrict__ b_v1,
    const float* __restrict__ w_rgb, const float* __restrict__ b_rgb,
    const float* __restrict__ betap, float* __restrict__ out)
{
    const int ray  = blockIdx.x;        // 0..8191
    const int tid  = threadIdx.x;       // 0..255, owns neuron `tid`
    const int lane = tid & 63;
    const int wv   = tid >> 6;
    const int bat  = ray >> 12;         // batch index (4096 rays per batch)

    __shared__ float samp[NPP][INDIM];      // sampled features, 9.2 KB
    __shared__ float denc[VD];              // viewdir encoding (per-ray)
    __shared__ float sdfl[NPP];
    __shared__ float wtsl[NPP];             // render weights
    __shared__ float h2l[NPP][WH];          // hidden activations, 24.6 KB
    __shared__ float red4[4][NPP];          // sdf wave partials
    __shared__ float redrgb[4][NPP][3];     // rgb wave partials
    __shared__ float rgbacc[NPP][3];

    const float nearv  = nearp[0];
    const float inv_fn = 2.0f / (farp[0] - nearv);
    const float beta   = betap[0];

    // ---------- phase 1: triplane bilinear sampling into LDS ----------
    for (int s = tid; s < NPP * INDIM; s += 256) {
        const int p  = s / INDIM;
        const int j  = s - p * INDIM;
        const int pl = j >> 5;          // plane 0,1,2
        const int c  = j & 31;          // channel
        const float* pp = pts + (ray * NPP + p) * 3;
        float cx, cy;
        if (pl == 0)      { cx = pp[0]; cy = pp[1]; }
        else if (pl == 1) { cx = pp[0]; cy = pp[2]; }
        else              { cx = pp[1]; cy = pp[2]; }
        cx = (cx - nearv) * inv_fn - 1.0f;     // -> [-1,1]
        cy = (cy - nearv) * inv_fn - 1.0f;
        const float fx = ((cx + 1.0f) * (float)RES - 1.0f) * 0.5f;
        const float fy = ((cy + 1.0f) * (float)RES - 1.0f) * 0.5f;
        const float fx0 = floorf(fx), fy0 = floorf(fy);
        const int   x0 = (int)fx0,    y0 = (int)fy0;
        const float wx = fx - fx0,    wy = fy - fy0;
        const float* base = planes + (((size_t)((bat * 3 + pl) * CP + c)) << 16);
        float acc = 0.0f;
        #pragma unroll
        for (int dy = 0; dy < 2; ++dy) {
            #pragma unroll
            for (int dx = 0; dx < 2; ++dx) {
                const int ix = x0 + dx, iy = y0 + dy;
                const bool valid = (ix >= 0) & (ix < RES) & (iy >= 0) & (iy < RES);
                const int cix = min(max(ix, 0), RES - 1);
                const int ciy = min(max(iy, 0), RES - 1);
                const float w = (dx ? wx : 1.0f - wx) * (dy ? wy : 1.0f - wy);
                acc += base[ciy * RES + cix] * (valid ? w : 0.0f);
            }
        }
        samp[p][j] = acc;
    }
    // viewdir positional encoding (per-ray, 27 values)
    if (tid < VD) {
        const int j = tid;
        float v;
        if (j < 3) {
            v = viewdirs[ray * 3 + j];
        } else if (j < 15) {
            const int k = (j - 3) / 3, cc = (j - 3) % 3;
            v = sinf((float)(1 << k) * 3.14159265358979323846f * viewdirs[ray * 3 + cc]);
        } else {
            const int k = (j - 15) / 3, cc = (j - 15) % 3;
            v = cosf((float)(1 << k) * 3.14159265358979323846f * viewdirs[ray * 3 + cc]);
        }
        denc[j] = v;
    }
    __syncthreads();

    float acc[NPP];

    // ---------- phase 2: sigma branch: h = softplus(samp@W0^T+b0); sdf = h@w1+b1 ----------
    #pragma unroll
    for (int p = 0; p < NPP; ++p) acc[p] = 0.0f;
    {
        const float* wrow = w_sig0 + tid * INDIM;   // row is 384B -> 16B aligned
        #pragma unroll 2
        for (int k = 0; k < INDIM; k += 4) {
            const float4 w4 = *reinterpret_cast<const float4*>(&wrow[k]);
            #pragma unroll
            for (int p = 0; p < NPP; ++p) {
                const float4 s4 = *reinterpret_cast<const float4*>(&samp[p][k]);
                acc[p] += s4.x * w4.x + s4.y * w4.y + s4.z * w4.z + s4.w * w4.w;
            }
        }
    }
    {
        const float b0 = b_sig0[tid], w1 = w_sig1[tid];
        #pragma unroll
        for (int p = 0; p < NPP; ++p) {
            float h = softplusf(acc[p] + b0) * w1;
            #pragma unroll
            for (int off = 32; off >= 1; off >>= 1)
                h += __shfl_xor(h, off, 64);
            if (lane == 0) red4[wv][p] = h;
        }
    }
    __syncthreads();
    if (tid < NPP) {
        const float s = red4[0][tid] + red4[1][tid] + red4[2][tid] + red4[3][tid] + b_sig1[0];
        sdfl[tid] = s;
        out[SDF_OFF + ray * NPP + tid] = s;
    }
    __syncthreads();

    // ---------- phase 3: render weights (serial N=24, thread 0) ----------
    if (tid == 0) {
        const float dx = rays_d[ray*3], dy = rays_d[ray*3+1], dz = rays_d[ray*3+2];
        const float nrm = sqrtf(dx*dx + dy*dy + dz*dz);
        float T = 1.0f;
        #pragma unroll
        for (int p = 0; p < NPP; ++p) {
            const float dist = ((p < NPP-1) ? (z_vals[ray*NPP+p+1] - z_vals[ray*NPP+p])
                                            : 1.0e10f) * nrm;
            const float sg    = sigmoidf_(-sdfl[p] / beta) / beta;
            const float alpha = 1.0f - expf(-sg * dist);
            wtsl[p] = alpha * T;
            T *= (1.0f - alpha + 1e-10f);
        }
        out[MASK_OFF + ray] = wtsl[NPP-1];
    }
    __syncthreads();
    if (tid < 3) {
        float a = 0.0f;
        #pragma unroll
        for (int p = 0; p < NPP; ++p) a += wtsl[p] * pts[(ray*NPP+p)*3 + tid];
        out[XYZ_OFF + ray*3 + tid] = a;
    }

    // ---------- phase 4: h2 = softplus([samp,denc]@Wv0^T + b) ----------
    #pragma unroll
    for (int p = 0; p < NPP; ++p) acc[p] = 0.0f;
    {
        const float* wrow = w_v0 + tid * (INDIM + VD);  // 123-float rows: NOT 16B aligned -> scalar w loads
        #pragma unroll 2
        for (int k = 0; k < INDIM; k += 4) {
            const float w0 = wrow[k], w1 = wrow[k+1], w2 = wrow[k+2], w3 = wrow[k+3];
            #pragma unroll
            for (int p = 0; p < NPP; ++p) {
                const float4 s4 = *reinterpret_cast<const float4*>(&samp[p][k]);
                acc[p] += s4.x * w0 + s4.y * w1 + s4.z * w2 + s4.w * w3;
            }
        }
        float dacc = 0.0f;   // viewdir-encoding part is per-ray uniform
        #pragma unroll
        for (int k = 0; k < VD; ++k) dacc += wrow[INDIM + k] * denc[k];
        const float b0 = b_v0[tid] + dacc;
        #pragma unroll
        for (int p = 0; p < NPP; ++p) h2l[p][tid] = softplusf(acc[p] + b0);
    }
    __syncthreads();

    // ---------- phase 5: features = h2@Wv1^T + b ----------
    #pragma unroll
    for (int p = 0; p < NPP; ++p) acc[p] = 0.0f;
    {
        const float* wrow = w_v1 + tid * WH;   // 1KB rows -> aligned
        #pragma unroll 2
        for (int n = 0; n < WH; n += 4) {
            const float4 w4 = *reinterpret_cast<const float4*>(&wrow[n]);
            #pragma unroll
            for (int p = 0; p < NPP; ++p) {
                const float4 h4 = *reinterpret_cast<const float4*>(&h2l[p][n]);
                acc[p] += h4.x * w4.x + h4.y * w4.y + h4.z * w4.z + h4.w * w4.w;
            }
        }
        const float b1 = b_v1[tid];
        #pragma unroll
        for (int p = 0; p < NPP; ++p) acc[p] += b1;
    }
    // feature_map = sum_p wts[p] * feat[p]  (thread owns feature channel tid)
    {
        float fm = 0.0f;
        #pragma unroll
        for (int p = 0; p < NPP; ++p) fm += wtsl[p] * acc[p];
        out[FEAT_OFF + ray * WH + tid] = fm;
    }

    // ---------- phase 6: rgb = feat@Wrgb^T + b, render ----------
    {
        const float wr0 = w_rgb[tid], wr1 = w_rgb[WH + tid], wr2 = w_rgb[2*WH + tid];
        #pragma unroll
        for (int p = 0; p < NPP; ++p) {
            float r0 = acc[p]*wr0, r1 = acc[p]*wr1, r2 = acc[p]*wr2;
            #pragma unroll
            for (int off = 32; off >= 1; off >>= 1) {
                r0 += __shfl_xor(r0, off, 64);
                r1 += __shfl_xor(r1, off, 64);
                r2 += __shfl_xor(r2, off, 64);
            }
            if (lane == 0) { redrgb[wv][p][0] = r0; redrgb[wv][p][1] = r1; redrgb[wv][p][2] = r2; }
        }
    }
    __syncthreads();
    if (tid < NPP) {
        const int p = tid;
        #pragma unroll
        for (int c = 0; c < 3; ++c) {
            const float rv = redrgb[0][p][c] + redrgb[1][p][c] + redrgb[2][p][c]
                           + redrgb[3][p][c] + b_rgb[c];
            rgbacc[p][c] = wtsl[p] * sigmoidf_(rv);
        }
    }
    __syncthreads();
    if (tid < 3) {
        float a = 0.0f;
        #pragma unroll
        for (int p = 0; p < NPP; ++p) a += rgbacc[p][tid];
        out[RGB_OFF + ray*3 + tid] = -1.0f + 2.0f * a;
    }
}

extern "C" void kernel_launch(void* const* d_in, const int* in_sizes, int n_in,
                              void* d_out, int out_size, void* d_ws, size_t ws_size,
                              hipStream_t stream) {
    const float* planes   = (const float*)d_in[0];
    const float* pts      = (const float*)d_in[1];
    const float* rays_d   = (const float*)d_in[2];
    const float* viewdirs = (const float*)d_in[3];
    const float* z_vals   = (const float*)d_in[4];
    const float* nearp    = (const float*)d_in[5];
    const float* farp     = (const float*)d_in[6];
    const float* w_sig0   = (const float*)d_in[7];
    const float* b_sig0   = (const float*)d_in[8];
    const float* w_sig1   = (const float*)d_in[9];
    const float* b_sig1   = (const float*)d_in[10];
    const float* w_v0     = (const float*)d_in[11];
    const float* b_v0     = (const float*)d_in[12];
    const float* w_v1     = (const float*)d_in[13];
    const float* b_v1     = (const float*)d_in[14];
    const float* w_rgb    = (const float*)d_in[15];
    const float* b_rgb    = (const float*)d_in[16];
    const float* betap    = (const float*)d_in[17];
    float* out = (float*)d_out;

    triplane_fused<<<NRAYS, 256, 0, stream>>>(
        planes, pts, rays_d, viewdirs, z_vals, nearp, farp,
        w_sig0, b_sig0, w_sig1, b_sig1, w_v0, b_v0, w_v1, b_v1,
        w_rgb, b_rgb, betap, out);
}

// Round 2
// 814.617 us; speedup vs baseline: 1.7875x; 1.7875x over previous
//
#include <hip/hip_runtime.h>
#include <math.h>

#define NPP 24
#define RES 256
#define WH  256
#define VD  27

// output chunk offsets (flat f32)
#define RGB_OFF  0
#define FEAT_OFF 24576
#define SDF_OFF  2121728
#define MASK_OFF 2318336
#define XYZ_OFF  2326528

typedef __attribute__((ext_vector_type(8))) short bf16x8;   // MFMA A/B frag (4 VGPRs)
typedef __attribute__((ext_vector_type(4))) float f32x4;    // MFMA C/D frag

__device__ __forceinline__ unsigned short f2bf(float f) {   // RNE f32->bf16
    unsigned int u = __builtin_bit_cast(unsigned int, f);
    u += 0x7FFFu + ((u >> 16) & 1u);
    return (unsigned short)(u >> 16);
}
__device__ __forceinline__ float bf2f(unsigned short s) {
    unsigned int u = ((unsigned int)s) << 16;
    return __builtin_bit_cast(float, u);
}
__device__ __forceinline__ float softplusf(float x) {
    return fmaxf(x, 0.0f) + log1pf(expf(-fabsf(x)));
}
__device__ __forceinline__ float sigmoidf_(float x) { return 1.0f / (1.0f + expf(-x)); }

// LDS XOR swizzle: flip 8-elem group by row&7 -> A-frag ds_read_b128 is 2-way (free)
__device__ __forceinline__ int swzA(int row, int col) { return (row * 128 + col) ^ ((row & 7) << 3); }
__device__ __forceinline__ int swzH(int row, int col) { return (row * 256 + col) ^ ((row & 7) << 3); }

// ---- weight pre-conversion: f32 -> bf16 into d_ws ----
// layout (ushort offsets): ws0[256*96] @0 | wv0pad[256*128] @24576 | wv1[256*256] @57344
__global__ void conv_weights(const float* __restrict__ ws0f, const float* __restrict__ wv0f,
                             const float* __restrict__ wv1f, unsigned short* __restrict__ ws) {
    int i = blockIdx.x * 256 + threadIdx.x;        // grid covers 65536
    if (i < 24576) ws[i] = f2bf(ws0f[i]);
    if (i < 32768) {
        int n = i >> 7, k = i & 127;
        ws[24576 + i] = (k < 123) ? f2bf(wv0f[n * 123 + k]) : (unsigned short)0;
    }
    if (i < 65536) ws[57344 + i] = f2bf(wv1f[i]);
}

__global__ __launch_bounds__(256) void triplane_mfma(
    const float* __restrict__ planes, const float* __restrict__ pts,
    const float* __restrict__ rays_d, const float* __restrict__ viewdirs,
    const float* __restrict__ z_vals, const float* __restrict__ nearp,
    const float* __restrict__ farp,
    const float* __restrict__ b_sig0, const float* __restrict__ w_sig1,
    const float* __restrict__ b_sig1, const float* __restrict__ b_v0,
    const float* __restrict__ b_v1,  const float* __restrict__ w_rgb,
    const float* __restrict__ b_rgb, const float* __restrict__ betap,
    const unsigned short* __restrict__ wbf, float* __restrict__ out)
{
    const int tid  = threadIdx.x;
    const int lane = tid & 63;
    const int wv   = tid >> 6;      // wave 0..3 owns cols [wv*64, wv*64+64)
    const int grp  = lane >> 4;     // 16-lane group 0..3
    const int l15  = lane & 15;
    const int ray0 = blockIdx.x * 2;
    const int bat  = ray0 >> 12;    // batch (4096 rays each); ray0 even -> same bat for both rays

    __shared__ __align__(16) unsigned short samp_lds[48 * 128]; // [row][k] bf16, swizzled
    __shared__ __align__(16) unsigned short h2_lds[48 * 256];   // [row][n] bf16, swizzled (reused for F)
    __shared__ float4 cinfo[48][3];
    __shared__ unsigned short denc2[2][32];
    __shared__ float sdf_part[4][48];
    __shared__ float sdfl[48];
    __shared__ float wtsl[48];
    __shared__ float rgbp[48][3];

    const float nearv  = nearp[0];
    const float inv_fn = 2.0f / (farp[0] - nearv);

    // ---------- phase 0: per-(row,plane) corner info + viewdir encoding ----------
    if (tid < 144) {
        const int row = tid / 3, pl = tid - 3 * (tid / 3);
        const float* pp = pts + (ray0 * NPP + row) * 3;   // global point = ray0*24 + row
        float cx, cy;
        if (pl == 0)      { cx = pp[0]; cy = pp[1]; }
        else if (pl == 1) { cx = pp[0]; cy = pp[2]; }
        else              { cx = pp[1]; cy = pp[2]; }
        cx = (cx - nearv) * inv_fn - 1.0f;
        cy = (cy - nearv) * inv_fn - 1.0f;
        const float fx = ((cx + 1.0f) * 256.0f - 1.0f) * 0.5f;
        const float fy = ((cy + 1.0f) * 256.0f - 1.0f) * 0.5f;
        const float fx0 = floorf(fx), fy0 = floorf(fy);
        cinfo[row][pl] = make_float4(fx0, fy0, fx - fx0, fy - fy0);
    }
    if (tid < 64) {
        const int r = tid >> 5, j = tid & 31;
        float v = 0.0f;
        if (j < VD) {
            const float* vd = viewdirs + (ray0 + r) * 3;
            if (j < 3) v = vd[j];
            else if (j < 15) { int k = (j - 3) / 3, c = (j - 3) % 3;
                v = sinf((float)(1 << k) * 3.14159265358979323846f * vd[c]); }
            else { int k = (j - 15) / 3, c = (j - 15) % 3;
                v = cosf((float)(1 << k) * 3.14159265358979323846f * vd[c]); }
        }
        denc2[r][j] = f2bf(v);
    }
    __syncthreads();

    // ---------- phase 1: bilinear gather (48 rows x 96 ch) + denc spread ----------
    #pragma unroll
    for (int it = 0; it < 18; ++it) {
        const int s = tid + it * 256;          // 0..4607
        const int row = s / 96, j = s - row * 96;
        const int pl = j >> 5, c = j & 31;
        const float4 ci = cinfo[row][pl];
        const int x0 = (int)ci.x, y0 = (int)ci.y;
        const float wx = ci.z, wy = ci.w;
        const float* base = planes + (((size_t)((bat * 3 + pl) * 32 + c)) << 16);
        float acc = 0.0f;
        #pragma unroll
        for (int dy = 0; dy < 2; ++dy)
        #pragma unroll
        for (int dx = 0; dx < 2; ++dx) {
            const int ix = x0 + dx, iy = y0 + dy;
            const bool valid = (ix >= 0) & (ix < RES) & (iy >= 0) & (iy < RES);
            const int cix = min(max(ix, 0), RES - 1);
            const int ciy = min(max(iy, 0), RES - 1);
            const float w = (dx ? wx : 1.0f - wx) * (dy ? wy : 1.0f - wy);
            acc += base[ciy * RES + cix] * (valid ? w : 0.0f);
        }
        samp_lds[swzA(row, j)] = f2bf(acc);
    }
    #pragma unroll
    for (int it = 0; it < 6; ++it) {
        const int s = tid + it * 256;          // 0..1535
        const int row = s >> 5, j = s & 31;
        samp_lds[swzA(row, 96 + j)] = denc2[row >= 24][j];   // cols 96..122 denc, 123..127 zero
    }
    __syncthreads();

    const unsigned short* ws0 = wbf;
    const unsigned short* wv0w = wbf + 24576;
    const unsigned short* wv1w = wbf + 57344;
    const f32x4 fzero = {0.0f, 0.0f, 0.0f, 0.0f};

    f32x4 acc[3][4];

    // ---------- sig0: H[48x256] = samp[48x96] @ Wsig0^T ----------
    #pragma unroll
    for (int mt = 0; mt < 3; ++mt)
        #pragma unroll
        for (int nt = 0; nt < 4; ++nt) acc[mt][nt] = fzero;
    #pragma unroll
    for (int ks = 0; ks < 3; ++ks) {
        bf16x8 a[3];
        #pragma unroll
        for (int mt = 0; mt < 3; ++mt)
            a[mt] = *(const bf16x8*)(samp_lds + swzA(mt * 16 + l15, ks * 32 + 8 * grp));
        #pragma unroll
        for (int nt = 0; nt < 4; ++nt) {
            const int n = wv * 64 + nt * 16 + l15;
            const bf16x8 b = *(const bf16x8*)(ws0 + n * 96 + ks * 32 + 8 * grp);
            #pragma unroll
            for (int mt = 0; mt < 3; ++mt)
                acc[mt][nt] = __builtin_amdgcn_mfma_f32_16x16x32_bf16(a[mt], b, acc[mt][nt], 0, 0, 0);
        }
    }
    // sdf partials: lane holds (row = mt*16+4*grp+r, col = wv*64+nt*16+l15)
    {
        float b0c[4], w1c[4];
        #pragma unroll
        for (int nt = 0; nt < 4; ++nt) {
            const int col = wv * 64 + nt * 16 + l15;
            b0c[nt] = b_sig0[col]; w1c[nt] = w_sig1[col];
        }
        #pragma unroll
        for (int mt = 0; mt < 3; ++mt)
        #pragma unroll
        for (int r = 0; r < 4; ++r) {
            float s = 0.0f;
            #pragma unroll
            for (int nt = 0; nt < 4; ++nt)
                s += softplusf(acc[mt][nt][r] + b0c[nt]) * w1c[nt];
            s += __shfl_xor(s, 1, 64); s += __shfl_xor(s, 2, 64);
            s += __shfl_xor(s, 4, 64); s += __shfl_xor(s, 8, 64);
            if (l15 == 0) sdf_part[wv][mt * 16 + 4 * grp + r] = s;
        }
    }
    __syncthreads();
    if (tid < 48) {
        const float s = sdf_part[0][tid] + sdf_part[1][tid] + sdf_part[2][tid]
                      + sdf_part[3][tid] + b_sig1[0];
        sdfl[tid] = s;
        out[SDF_OFF + ray0 * NPP + tid] = s;
    }
    __syncthreads();
    // render weights (serial N=24, one thread per ray) — overlaps v0 MFMA below
    if (tid < 2) {
        const int ray = ray0 + tid;
        const float dx = rays_d[ray * 3], dy = rays_d[ray * 3 + 1], dz = rays_d[ray * 3 + 2];
        const float nrm = sqrtf(dx * dx + dy * dy + dz * dz);
        const float beta = betap[0];
        float T = 1.0f;
        #pragma unroll
        for (int p = 0; p < NPP; ++p) {
            const float dist = ((p < NPP - 1) ? (z_vals[ray * NPP + p + 1] - z_vals[ray * NPP + p])
                                              : 1.0e10f) * nrm;
            const float sg = sigmoidf_(-sdfl[tid * NPP + p] / beta) / beta;
            const float alpha = 1.0f - expf(-sg * dist);
            wtsl[tid * NPP + p] = alpha * T;
            T *= (1.0f - alpha + 1e-10f);
        }
        out[MASK_OFF + ray] = wtsl[tid * NPP + NPP - 1];
    }

    // ---------- v0: H2[48x256] = [samp|denc][48x128] @ Wv0pad^T ----------
    #pragma unroll
    for (int mt = 0; mt < 3; ++mt)
        #pragma unroll
        for (int nt = 0; nt < 4; ++nt) acc[mt][nt] = fzero;
    #pragma unroll
    for (int ks = 0; ks < 4; ++ks) {
        bf16x8 a[3];
        #pragma unroll
        for (int mt = 0; mt < 3; ++mt)
            a[mt] = *(const bf16x8*)(samp_lds + swzA(mt * 16 + l15, ks * 32 + 8 * grp));
        #pragma unroll
        for (int nt = 0; nt < 4; ++nt) {
            const int n = wv * 64 + nt * 16 + l15;
            const bf16x8 b = *(const bf16x8*)(wv0w + n * 128 + ks * 32 + 8 * grp);
            #pragma unroll
            for (int mt = 0; mt < 3; ++mt)
                acc[mt][nt] = __builtin_amdgcn_mfma_f32_16x16x32_bf16(a[mt], b, acc[mt][nt], 0, 0, 0);
        }
    }
    #pragma unroll
    for (int nt = 0; nt < 4; ++nt) {
        const int col = wv * 64 + nt * 16 + l15;
        const float bv = b_v0[col];
        #pragma unroll
        for (int mt = 0; mt < 3; ++mt)
        #pragma unroll
        for (int r = 0; r < 4; ++r) {
            const int row = mt * 16 + 4 * grp + r;
            h2_lds[swzH(row, col)] = f2bf(softplusf(acc[mt][nt][r] + bv));
        }
    }
    __syncthreads();   // h2 complete + wtsl complete
    if (tid < 6) {
        const int rr = tid / 3, c = tid - rr * 3;
        float a = 0.0f;
        #pragma unroll
        for (int p = 0; p < NPP; ++p)
            a += wtsl[rr * NPP + p] * pts[(ray0 * NPP + rr * NPP + p) * 3 + c];
        out[XYZ_OFF + (ray0 + rr) * 3 + c] = a;
    }

    // ---------- v1: F[48x256] = H2[48x256] @ Wv1^T ----------
    #pragma unroll
    for (int mt = 0; mt < 3; ++mt)
        #pragma unroll
        for (int nt = 0; nt < 4; ++nt) acc[mt][nt] = fzero;
    #pragma unroll
    for (int ks = 0; ks < 8; ++ks) {
        bf16x8 a[3];
        #pragma unroll
        for (int mt = 0; mt < 3; ++mt)
            a[mt] = *(const bf16x8*)(h2_lds + swzH(mt * 16 + l15, ks * 32 + 8 * grp));
        #pragma unroll
        for (int nt = 0; nt < 4; ++nt) {
            const int n = wv * 64 + nt * 16 + l15;
            const bf16x8 b = *(const bf16x8*)(wv1w + n * 256 + ks * 32 + 8 * grp);
            #pragma unroll
            for (int mt = 0; mt < 3; ++mt)
                acc[mt][nt] = __builtin_amdgcn_mfma_f32_16x16x32_bf16(a[mt], b, acc[mt][nt], 0, 0, 0);
        }
    }
    __syncthreads();   // all v1 reads of h2_lds done before overwrite with F

    // F = acc + b_v1; feature_map (f32) + store F bf16 for rgb
    #pragma unroll
    for (int nt = 0; nt < 4; ++nt) {
        const int col = wv * 64 + nt * 16 + l15;
        const float bv = b_v1[col];
        float fm0 = 0.0f, fm1 = 0.0f;
        #pragma unroll
        for (int mt = 0; mt < 3; ++mt)
        #pragma unroll
        for (int r = 0; r < 4; ++r) {
            const int row = mt * 16 + 4 * grp + r;
            const float F = acc[mt][nt][r] + bv;
            h2_lds[swzH(row, col)] = f2bf(F);
            const float wf = wtsl[row] * F;
            if (row < NPP) fm0 += wf; else fm1 += wf;
        }
        fm0 += __shfl_xor(fm0, 16, 64); fm0 += __shfl_xor(fm0, 32, 64);
        fm1 += __shfl_xor(fm1, 16, 64); fm1 += __shfl_xor(fm1, 32, 64);
        if (grp == 0) {
            out[FEAT_OFF + ray0 * WH + col] = fm0;
            out[FEAT_OFF + (ray0 + 1) * WH + col] = fm1;
        }
    }
    __syncthreads();

    // ---------- rgb: rgb[p][c] = sigmoid(F[p] . w_rgb[c] + b_rgb[c]) ----------
    if (tid < 144) {
        const int c = tid / 48, p = tid - c * 48;
        float accr = 0.0f;
        #pragma unroll
        for (int j = 0; j < 32; ++j) {
            const bf16x8 v = *(const bf16x8*)(h2_lds + swzH(p, 8 * j));
            const float4 w0 = *(const float4*)(w_rgb + c * WH + 8 * j);
            const float4 w1 = *(const float4*)(w_rgb + c * WH + 8 * j + 4);
            accr += bf2f((unsigned short)v[0]) * w0.x + bf2f((unsigned short)v[1]) * w0.y
                  + bf2f((unsigned short)v[2]) * w0.z + bf2f((unsigned short)v[3]) * w0.w
                  + bf2f((unsigned short)v[4]) * w1.x + bf2f((unsigned short)v[5]) * w1.y
                  + bf2f((unsigned short)v[6]) * w1.z + bf2f((unsigned short)v[7]) * w1.w;
        }
        rgbp[p][c] = wtsl[p] * sigmoidf_(accr + b_rgb[c]);
    }
    __syncthreads();
    if (tid < 6) {
        const int rr = tid / 3, c = tid - rr * 3;
        float s = 0.0f;
        #pragma unroll
        for (int p = 0; p < NPP; ++p) s += rgbp[rr * NPP + p][c];
        out[RGB_OFF + (ray0 + rr) * 3 + c] = -1.0f + 2.0f * s;
    }
}

extern "C" void kernel_launch(void* const* d_in, const int* in_sizes, int n_in,
                              void* d_out, int out_size, void* d_ws, size_t ws_size,
                              hipStream_t stream) {
    const float* planes   = (const float*)d_in[0];
    const float* pts      = (const float*)d_in[1];
    const float* rays_d   = (const float*)d_in[2];
    const float* viewdirs = (const float*)d_in[3];
    const float* z_vals   = (const float*)d_in[4];
    const float* nearp    = (const float*)d_in[5];
    const float* farp     = (const float*)d_in[6];
    const float* w_sig0   = (const float*)d_in[7];
    const float* b_sig0   = (const float*)d_in[8];
    const float* w_sig1   = (const float*)d_in[9];
    const float* b_sig1   = (const float*)d_in[10];
    const float* w_v0     = (const float*)d_in[11];
    const float* b_v0     = (const float*)d_in[12];
    const float* w_v1     = (const float*)d_in[13];
    const float* b_v1     = (const float*)d_in[14];
    const float* w_rgb    = (const float*)d_in[15];
    const float* b_rgb    = (const float*)d_in[16];
    const float* betap    = (const float*)d_in[17];
    float* out = (float*)d_out;
    unsigned short* wbf = (unsigned short*)d_ws;   // 245,760 B used

    conv_weights<<<256, 256, 0, stream>>>(w_sig0, w_v0, w_v1, wbf);
    triplane_mfma<<<4096, 256, 0, stream>>>(
        planes, pts, rays_d, viewdirs, z_vals, nearp, farp,
        b_sig0, w_sig1, b_sig1, b_v0, b_v1, w_rgb, b_rgb, betap, wbf, out);
}

// Round 3
// 442.678 us; speedup vs baseline: 3.2893x; 1.8402x over previous
//
#include <hip/hip_runtime.h>
#include <math.h>

#define NPP 24
#define RES 256
#define WH  256
#define VD  27

// output chunk offsets (flat f32)
#define RGB_OFF  0
#define FEAT_OFF 24576
#define SDF_OFF  2121728
#define MASK_OFF 2318336
#define XYZ_OFF  2326528

typedef __attribute__((ext_vector_type(8))) short bf16x8;   // MFMA A/B frag (4 VGPRs)
typedef __attribute__((ext_vector_type(8))) unsigned short u16x8;
typedef __attribute__((ext_vector_type(4))) float f32x4;    // MFMA C/D frag

__device__ __forceinline__ unsigned short f2bf(float f) {   // RNE f32->bf16
    unsigned int u = __builtin_bit_cast(unsigned int, f);
    u += 0x7FFFu + ((u >> 16) & 1u);
    return (unsigned short)(u >> 16);
}
__device__ __forceinline__ float bf2f(unsigned short s) {
    unsigned int u = ((unsigned int)s) << 16;
    return __builtin_bit_cast(float, u);
}
__device__ __forceinline__ float softplusf(float x) {
    return fmaxf(x, 0.0f) + log1pf(expf(-fabsf(x)));
}
__device__ __forceinline__ float sigmoidf_(float x) { return 1.0f / (1.0f + expf(-x)); }

// LDS XOR swizzle: flip 8-elem group by row&7 -> A-frag ds_read_b128 is 2-way (free)
__device__ __forceinline__ int swzA(int row, int col) { return (row * 128 + col) ^ ((row & 7) << 3); }
__device__ __forceinline__ int swzH(int row, int col) { return (row * 256 + col) ^ ((row & 7) << 3); }

// ---- weight pre-conversion: f32 -> bf16 into d_ws ----
// layout (ushort offsets): ws0[256*96] @0 | wv0pad[256*128] @24576 | wv1[256*256] @57344
__global__ void conv_weights(const float* __restrict__ ws0f, const float* __restrict__ wv0f,
                             const float* __restrict__ wv1f, unsigned short* __restrict__ ws) {
    int i = blockIdx.x * 256 + threadIdx.x;        // grid covers 65536
    if (i < 24576) ws[i] = f2bf(ws0f[i]);
    if (i < 32768) {
        int n = i >> 7, k = i & 127;
        ws[24576 + i] = (k < 123) ? f2bf(wv0f[n * 123 + k]) : (unsigned short)0;
    }
    if (i < 65536) ws[57344 + i] = f2bf(wv1f[i]);
}

// ---- plane transpose: [6][32][256][256] f32 -> [6][256][256][32] bf16 ----
// block = one (pl6, y, xtile64): reads 32ch x 64x, writes 4KB contiguous
__global__ __launch_bounds__(256) void transpose_planes(const float* __restrict__ planes,
                                                        unsigned short* __restrict__ tr) {
    __shared__ float lds[64][34];
    const int b = blockIdx.x;              // 0..6143
    const int pl6 = b >> 10;               // 0..5
    const int rem = b & 1023;
    const int y = rem >> 2;
    const int x0 = (rem & 3) << 6;
    const int t = threadIdx.x;
    const float* src = planes + ((size_t)pl6 << 21) + y * 256 + x0;  // + c*65536 + x
    #pragma unroll
    for (int it = 0; it < 8; ++it) {
        const int idx = t + it * 256;      // 0..2047
        const int c = idx >> 6, x = idx & 63;
        lds[x][c] = src[((size_t)c << 16) + x];
    }
    __syncthreads();
    unsigned short* dst = tr + ((((size_t)pl6 << 16) + (y << 8) + x0) << 5);  // *32 ch
    const int x = t >> 2, c0 = (t & 3) << 3;
    u16x8 v;
    #pragma unroll
    for (int j = 0; j < 8; ++j) v[j] = f2bf(lds[x][c0 + j]);
    *reinterpret_cast<u16x8*>(dst + t * 8) = v;
}

__global__ __launch_bounds__(256) void triplane_mfma(
    const float* __restrict__ planes, const float* __restrict__ pts,
    const float* __restrict__ rays_d, const float* __restrict__ viewdirs,
    const float* __restrict__ z_vals, const float* __restrict__ nearp,
    const float* __restrict__ farp,
    const float* __restrict__ b_sig0, const float* __restrict__ w_sig1,
    const float* __restrict__ b_sig1, const float* __restrict__ b_v0,
    const float* __restrict__ b_v1,  const float* __restrict__ w_rgb,
    const float* __restrict__ b_rgb, const float* __restrict__ betap,
    const unsigned short* __restrict__ wbf, const unsigned short* __restrict__ trp,
    float* __restrict__ out)
{
    const int tid  = threadIdx.x;
    const int lane = tid & 63;
    const int wv   = tid >> 6;      // wave 0..3 owns cols [wv*64, wv*64+64)
    const int grp  = lane >> 4;     // 16-lane group 0..3
    const int l15  = lane & 15;
    const int ray0 = blockIdx.x * 2;
    const int bat  = ray0 >> 12;    // batch (4096 rays each); ray0 even -> same bat for both rays

    __shared__ __align__(16) unsigned short samp_lds[48 * 128]; // [row][k] bf16, swizzled
    __shared__ __align__(16) unsigned short h2_lds[48 * 256];   // [row][n] bf16, swizzled (reused for F)
    __shared__ float4 cinfo[48][3];
    __shared__ unsigned short denc2[2][32];
    __shared__ float sdf_part[4][48];
    __shared__ float sdfl[48];
    __shared__ float wtsl[48];
    __shared__ float rgbp[48][3];

    const float nearv  = nearp[0];
    const float inv_fn = 2.0f / (farp[0] - nearv);

    // ---------- phase 0: per-(row,plane) corner info + viewdir encoding ----------
    if (tid < 144) {
        const int row = tid / 3, pl = tid - 3 * (tid / 3);
        const float* pp = pts + (ray0 * NPP + row) * 3;
        float cx, cy;
        if (pl == 0)      { cx = pp[0]; cy = pp[1]; }
        else if (pl == 1) { cx = pp[0]; cy = pp[2]; }
        else              { cx = pp[1]; cy = pp[2]; }
        cx = (cx - nearv) * inv_fn - 1.0f;
        cy = (cy - nearv) * inv_fn - 1.0f;
        const float fx = ((cx + 1.0f) * 256.0f - 1.0f) * 0.5f;
        const float fy = ((cy + 1.0f) * 256.0f - 1.0f) * 0.5f;
        const float fx0 = floorf(fx), fy0 = floorf(fy);
        cinfo[row][pl] = make_float4(fx0, fy0, fx - fx0, fy - fy0);
    }
    if (tid < 64) {
        const int r = tid >> 5, j = tid & 31;
        float v = 0.0f;
        if (j < VD) {
            const float* vd = viewdirs + (ray0 + r) * 3;
            if (j < 3) v = vd[j];
            else if (j < 15) { int k = (j - 3) / 3, c = (j - 3) % 3;
                v = sinf((float)(1 << k) * 3.14159265358979323846f * vd[c]); }
            else { int k = (j - 15) / 3, c = (j - 15) % 3;
                v = cosf((float)(1 << k) * 3.14159265358979323846f * vd[c]); }
        }
        denc2[r][j] = f2bf(v);
    }
    __syncthreads();

    // ---------- phase 1: bilinear gather ----------
    if (trp) {
        // fast path: channel-last bf16 planes; unit = (point-plane, 8-ch group)
        #pragma unroll
        for (int it = 0; it < 3; ++it) {
            const int u = tid + it * 256;
            if (u < 576) {
                const int pp = u >> 2, cg = u & 3;
                const int row = pp / 3, pl = pp - 3 * (pp / 3);
                const float4 ci = cinfo[row][pl];
                const int x0 = (int)ci.x, y0 = (int)ci.y;
                const float wx = ci.z, wy = ci.w;
                const bool vx0 = (x0 >= 0) & (x0 < RES), vx1 = (x0 + 1 >= 0) & (x0 + 1 < RES);
                const bool vy0 = (y0 >= 0) & (y0 < RES), vy1 = (y0 + 1 >= 0) & (y0 + 1 < RES);
                const float w00 = (vx0 & vy0) ? (1.0f - wx) * (1.0f - wy) : 0.0f;
                const float w10 = (vx1 & vy0) ? wx * (1.0f - wy) : 0.0f;
                const float w01 = (vx0 & vy1) ? (1.0f - wx) * wy : 0.0f;
                const float w11 = (vx1 & vy1) ? wx * wy : 0.0f;
                const int xc0 = min(max(x0, 0), RES - 1), xc1 = min(max(x0 + 1, 0), RES - 1);
                const int yc0 = min(max(y0, 0), RES - 1), yc1 = min(max(y0 + 1, 0), RES - 1);
                const unsigned short* bb = trp + (((size_t)(bat * 3 + pl)) << 21) + cg * 8;
                const u16x8 v00 = *reinterpret_cast<const u16x8*>(bb + (((yc0 << 8) + xc0) << 5));
                const u16x8 v10 = *reinterpret_cast<const u16x8*>(bb + (((yc0 << 8) + xc1) << 5));
                const u16x8 v01 = *reinterpret_cast<const u16x8*>(bb + (((yc1 << 8) + xc0) << 5));
                const u16x8 v11 = *reinterpret_cast<const u16x8*>(bb + (((yc1 << 8) + xc1) << 5));
                u16x8 r;
                #pragma unroll
                for (int j = 0; j < 8; ++j) {
                    const float a = w00 * bf2f(v00[j]) + w10 * bf2f(v10[j])
                                  + w01 * bf2f(v01[j]) + w11 * bf2f(v11[j]);
                    r[j] = f2bf(a);
                }
                *reinterpret_cast<u16x8*>(samp_lds + swzA(row, pl * 32 + cg * 8)) = r;
            }
        }
    } else {
        // fallback: channel-major f32 gather (slow, correct)
        #pragma unroll
        for (int it = 0; it < 18; ++it) {
            const int s = tid + it * 256;
            const int row = s / 96, j = s - row * 96;
            const int pl = j >> 5, c = j & 31;
            const float4 ci = cinfo[row][pl];
            const int x0 = (int)ci.x, y0 = (int)ci.y;
            const float wx = ci.z, wy = ci.w;
            const float* base = planes + (((size_t)((bat * 3 + pl) * 32 + c)) << 16);
            float acc = 0.0f;
            #pragma unroll
            for (int dy = 0; dy < 2; ++dy)
            #pragma unroll
            for (int dx = 0; dx < 2; ++dx) {
                const int ix = x0 + dx, iy = y0 + dy;
                const bool valid = (ix >= 0) & (ix < RES) & (iy >= 0) & (iy < RES);
                const int cix = min(max(ix, 0), RES - 1);
                const int ciy = min(max(iy, 0), RES - 1);
                const float w = (dx ? wx : 1.0f - wx) * (dy ? wy : 1.0f - wy);
                acc += base[ciy * RES + cix] * (valid ? w : 0.0f);
            }
            samp_lds[swzA(row, j)] = f2bf(acc);
        }
    }
    #pragma unroll
    for (int it = 0; it < 6; ++it) {
        const int s = tid + it * 256;          // 0..1535
        const int row = s >> 5, j = s & 31;
        samp_lds[swzA(row, 96 + j)] = denc2[row >= 24][j];   // cols 96..122 denc, 123..127 zero
    }
    __syncthreads();

    const unsigned short* ws0 = wbf;
    const unsigned short* wv0w = wbf + 24576;
    const unsigned short* wv1w = wbf + 57344;
    const f32x4 fzero = {0.0f, 0.0f, 0.0f, 0.0f};

    f32x4 acc[3][4];

    // ---------- sig0: H[48x256] = samp[48x96] @ Wsig0^T ----------
    #pragma unroll
    for (int mt = 0; mt < 3; ++mt)
        #pragma unroll
        for (int nt = 0; nt < 4; ++nt) acc[mt][nt] = fzero;
    #pragma unroll
    for (int ks = 0; ks < 3; ++ks) {
        bf16x8 a[3];
        #pragma unroll
        for (int mt = 0; mt < 3; ++mt)
            a[mt] = *(const bf16x8*)(samp_lds + swzA(mt * 16 + l15, ks * 32 + 8 * grp));
        #pragma unroll
        for (int nt = 0; nt < 4; ++nt) {
            const int n = wv * 64 + nt * 16 + l15;
            const bf16x8 b = *(const bf16x8*)(ws0 + n * 96 + ks * 32 + 8 * grp);
            #pragma unroll
            for (int mt = 0; mt < 3; ++mt)
                acc[mt][nt] = __builtin_amdgcn_mfma_f32_16x16x32_bf16(a[mt], b, acc[mt][nt], 0, 0, 0);
        }
    }
    // sdf partials
    {
        float b0c[4], w1c[4];
        #pragma unroll
        for (int nt = 0; nt < 4; ++nt) {
            const int col = wv * 64 + nt * 16 + l15;
            b0c[nt] = b_sig0[col]; w1c[nt] = w_sig1[col];
        }
        #pragma unroll
        for (int mt = 0; mt < 3; ++mt)
        #pragma unroll
        for (int r = 0; r < 4; ++r) {
            float s = 0.0f;
            #pragma unroll
            for (int nt = 0; nt < 4; ++nt)
                s += softplusf(acc[mt][nt][r] + b0c[nt]) * w1c[nt];
            s += __shfl_xor(s, 1, 64); s += __shfl_xor(s, 2, 64);
            s += __shfl_xor(s, 4, 64); s += __shfl_xor(s, 8, 64);
            if (l15 == 0) sdf_part[wv][mt * 16 + 4 * grp + r] = s;
        }
    }
    __syncthreads();
    if (tid < 48) {
        const float s = sdf_part[0][tid] + sdf_part[1][tid] + sdf_part[2][tid]
                      + sdf_part[3][tid] + b_sig1[0];
        sdfl[tid] = s;
        out[SDF_OFF + ray0 * NPP + tid] = s;
    }
    __syncthreads();
    // render weights (serial N=24, one thread per ray) — overlaps v0 MFMA below
    if (tid < 2) {
        const int ray = ray0 + tid;
        const float dx = rays_d[ray * 3], dy = rays_d[ray * 3 + 1], dz = rays_d[ray * 3 + 2];
        const float nrm = sqrtf(dx * dx + dy * dy + dz * dz);
        const float beta = betap[0];
        float T = 1.0f;
        #pragma unroll
        for (int p = 0; p < NPP; ++p) {
            const float dist = ((p < NPP - 1) ? (z_vals[ray * NPP + p + 1] - z_vals[ray * NPP + p])
                                              : 1.0e10f) * nrm;
            const float sg = sigmoidf_(-sdfl[tid * NPP + p] / beta) / beta;
            const float alpha = 1.0f - expf(-sg * dist);
            wtsl[tid * NPP + p] = alpha * T;
            T *= (1.0f - alpha + 1e-10f);
        }
        out[MASK_OFF + ray] = wtsl[tid * NPP + NPP - 1];
    }

    // ---------- v0: H2[48x256] = [samp|denc][48x128] @ Wv0pad^T ----------
    #pragma unroll
    for (int mt = 0; mt < 3; ++mt)
        #pragma unroll
        for (int nt = 0; nt < 4; ++nt) acc[mt][nt] = fzero;
    #pragma unroll
    for (int ks = 0; ks < 4; ++ks) {
        bf16x8 a[3];
        #pragma unroll
        for (int mt = 0; mt < 3; ++mt)
            a[mt] = *(const bf16x8*)(samp_lds + swzA(mt * 16 + l15, ks * 32 + 8 * grp));
        #pragma unroll
        for (int nt = 0; nt < 4; ++nt) {
            const int n = wv * 64 + nt * 16 + l15;
            const bf16x8 b = *(const bf16x8*)(wv0w + n * 128 + ks * 32 + 8 * grp);
            #pragma unroll
            for (int mt = 0; mt < 3; ++mt)
                acc[mt][nt] = __builtin_amdgcn_mfma_f32_16x16x32_bf16(a[mt], b, acc[mt][nt], 0, 0, 0);
        }
    }
    #pragma unroll
    for (int nt = 0; nt < 4; ++nt) {
        const int col = wv * 64 + nt * 16 + l15;
        const float bv = b_v0[col];
        #pragma unroll
        for (int mt = 0; mt < 3; ++mt)
        #pragma unroll
        for (int r = 0; r < 4; ++r) {
            const int row = mt * 16 + 4 * grp + r;
            h2_lds[swzH(row, col)] = f2bf(softplusf(acc[mt][nt][r] + bv));
        }
    }
    __syncthreads();   // h2 complete + wtsl complete
    if (tid < 6) {
        const int rr = tid / 3, c = tid - rr * 3;
        float a = 0.0f;
        #pragma unroll
        for (int p = 0; p < NPP; ++p)
            a += wtsl[rr * NPP + p] * pts[(ray0 * NPP + rr * NPP + p) * 3 + c];
        out[XYZ_OFF + (ray0 + rr) * 3 + c] = a;
    }

    // ---------- v1: F[48x256] = H2[48x256] @ Wv1^T ----------
    #pragma unroll
    for (int mt = 0; mt < 3; ++mt)
        #pragma unroll
        for (int nt = 0; nt < 4; ++nt) acc[mt][nt] = fzero;
    #pragma unroll
    for (int ks = 0; ks < 8; ++ks) {
        bf16x8 a[3];
        #pragma unroll
        for (int mt = 0; mt < 3; ++mt)
            a[mt] = *(const bf16x8*)(h2_lds + swzH(mt * 16 + l15, ks * 32 + 8 * grp));
        #pragma unroll
        for (int nt = 0; nt < 4; ++nt) {
            const int n = wv * 64 + nt * 16 + l15;
            const bf16x8 b = *(const bf16x8*)(wv1w + n * 256 + ks * 32 + 8 * grp);
            #pragma unroll
            for (int mt = 0; mt < 3; ++mt)
                acc[mt][nt] = __builtin_amdgcn_mfma_f32_16x16x32_bf16(a[mt], b, acc[mt][nt], 0, 0, 0);
        }
    }
    __syncthreads();   // all v1 reads of h2_lds done before overwrite with F

    // F = acc + b_v1; feature_map (f32) + store F bf16 for rgb
    #pragma unroll
    for (int nt = 0; nt < 4; ++nt) {
        const int col = wv * 64 + nt * 16 + l15;
        const float bv = b_v1[col];
        float fm0 = 0.0f, fm1 = 0.0f;
        #pragma unroll
        for (int mt = 0; mt < 3; ++mt)
        #pragma unroll
        for (int r = 0; r < 4; ++r) {
            const int row = mt * 16 + 4 * grp + r;
            const float F = acc[mt][nt][r] + bv;
            h2_lds[swzH(row, col)] = f2bf(F);
            const float wf = wtsl[row] * F;
            if (row < NPP) fm0 += wf; else fm1 += wf;
        }
        fm0 += __shfl_xor(fm0, 16, 64); fm0 += __shfl_xor(fm0, 32, 64);
        fm1 += __shfl_xor(fm1, 16, 64); fm1 += __shfl_xor(fm1, 32, 64);
        if (grp == 0) {
            out[FEAT_OFF + ray0 * WH + col] = fm0;
            out[FEAT_OFF + (ray0 + 1) * WH + col] = fm1;
        }
    }
    __syncthreads();

    // ---------- rgb ----------
    if (tid < 144) {
        const int c = tid / 48, p = tid - c * 48;
        float accr = 0.0f;
        #pragma unroll
        for (int j = 0; j < 32; ++j) {
            const bf16x8 v = *(const bf16x8*)(h2_lds + swzH(p, 8 * j));
            const float4 w0 = *(const float4*)(w_rgb + c * WH + 8 * j);
            const float4 w1 = *(const float4*)(w_rgb + c * WH + 8 * j + 4);
            accr += bf2f((unsigned short)v[0]) * w0.x + bf2f((unsigned short)v[1]) * w0.y
                  + bf2f((unsigned short)v[2]) * w0.z + bf2f((unsigned short)v[3]) * w0.w
                  + bf2f((unsigned short)v[4]) * w1.x + bf2f((unsigned short)v[5]) * w1.y
                  + bf2f((unsigned short)v[6]) * w1.z + bf2f((unsigned short)v[7]) * w1.w;
        }
        rgbp[p][c] = wtsl[p] * sigmoidf_(accr + b_rgb[c]);
    }
    __syncthreads();
    if (tid < 6) {
        const int rr = tid / 3, c = tid - rr * 3;
        float s = 0.0f;
        #pragma unroll
        for (int p = 0; p < NPP; ++p) s += rgbp[rr * NPP + p][c];
        out[RGB_OFF + (ray0 + rr) * 3 + c] = -1.0f + 2.0f * s;
    }
}

extern "C" void kernel_launch(void* const* d_in, const int* in_sizes, int n_in,
                              void* d_out, int out_size, void* d_ws, size_t ws_size,
                              hipStream_t stream) {
    const float* planes   = (const float*)d_in[0];
    const float* pts      = (const float*)d_in[1];
    const float* rays_d   = (const float*)d_in[2];
    const float* viewdirs = (const float*)d_in[3];
    const float* z_vals   = (const float*)d_in[4];
    const float* nearp    = (const float*)d_in[5];
    const float* farp     = (const float*)d_in[6];
    const float* w_sig0   = (const float*)d_in[7];
    const float* b_sig0   = (const float*)d_in[8];
    const float* w_sig1   = (const float*)d_in[9];
    const float* b_sig1   = (const float*)d_in[10];
    const float* w_v0     = (const float*)d_in[11];
    const float* b_v0     = (const float*)d_in[12];
    const float* w_v1     = (const float*)d_in[13];
    const float* b_v1     = (const float*)d_in[14];
    const float* w_rgb    = (const float*)d_in[15];
    const float* b_rgb    = (const float*)d_in[16];
    const float* betap    = (const float*)d_in[17];
    float* out = (float*)d_out;
    unsigned short* wbf = (unsigned short*)d_ws;        // 245,760 B weights @0

    const size_t TR_OFF_B = 262144;                     // 256 KB aligned
    const size_t TR_BYTES = (size_t)6 * 256 * 256 * 32 * 2;  // 24 MB
    unsigned short* trp = nullptr;
    if (ws_size >= TR_OFF_B + TR_BYTES) {
        trp = (unsigned short*)((char*)d_ws + TR_OFF_B);
        transpose_planes<<<6144, 256, 0, stream>>>(planes, trp);
    }
    conv_weights<<<256, 256, 0, stream>>>(w_sig0, w_v0, w_v1, wbf);
    triplane_mfma<<<4096, 256, 0, stream>>>(
        planes, pts, rays_d, viewdirs, z_vals, nearp, farp,
        b_sig0, w_sig1, b_sig1, b_v0, b_v1, w_rgb, b_rgb, betap, wbf, trp, out);
}

// Round 4
// 265.269 us; speedup vs baseline: 5.4892x; 1.6688x over previous
//
#include <hip/hip_runtime.h>
#include <math.h>

#define NPP 24
#define RES 256
#define WH  256
#define VD  27

// output chunk offsets (flat f32)
#define RGB_OFF  0
#define FEAT_OFF 24576
#define SDF_OFF  2121728
#define MASK_OFF 2318336
#define XYZ_OFF  2326528

typedef __attribute__((ext_vector_type(8))) short bf16x8;   // MFMA A/B frag (4 VGPRs)
typedef __attribute__((ext_vector_type(8))) unsigned short u16x8;
typedef __attribute__((ext_vector_type(4))) float f32x4;    // MFMA C/D frag

__device__ __forceinline__ unsigned short f2bf(float f) {   // RNE f32->bf16
    unsigned int u = __builtin_bit_cast(unsigned int, f);
    u += 0x7FFFu + ((u >> 16) & 1u);
    return (unsigned short)(u >> 16);
}
__device__ __forceinline__ float bf2f(unsigned short s) {
    unsigned int u = ((unsigned int)s) << 16;
    return __builtin_bit_cast(float, u);
}
// packed f32x2 -> bf16x2 (RNE), one v_cvt_pk_bf16_f32
__device__ __forceinline__ unsigned int cvtpk(float lo, float hi) {
    unsigned int r;
    asm("v_cvt_pk_bf16_f32 %0, %1, %2" : "=v"(r) : "v"(lo), "v"(hi));
    return r;
}
__device__ __forceinline__ float softplusf(float x) {
    // fast softplus: bf16 rounding of inputs dwarfs fast-math error
    return fmaxf(x, 0.0f) + __logf(1.0f + __expf(-fabsf(x)));
}
__device__ __forceinline__ float sigmoidf_(float x) { return 1.0f / (1.0f + __expf(-x)); }

// LDS XOR swizzle: flip 8-elem group by row&7 -> A-frag ds_read_b128 is 2-way (free)
__device__ __forceinline__ int swzA(int row, int col) { return (row * 128 + col) ^ ((row & 7) << 3); }
__device__ __forceinline__ int swzH(int row, int col) { return (row * 256 + col) ^ ((row & 7) << 3); }

// ---- weight pre-conversion: f32 -> bf16 into d_ws ----
// layout (ushort offsets): ws0[256*96] @0 | wv0pad[256*128] @24576 | wv1[256*256] @57344
__global__ void conv_weights(const float* __restrict__ ws0f, const float* __restrict__ wv0f,
                             const float* __restrict__ wv1f, unsigned short* __restrict__ ws) {
    int i = blockIdx.x * 256 + threadIdx.x;        // grid covers 65536
    if (i < 24576) ws[i] = f2bf(ws0f[i]);
    if (i < 32768) {
        int n = i >> 7, k = i & 127;
        ws[24576 + i] = (k < 123) ? f2bf(wv0f[n * 123 + k]) : (unsigned short)0;
    }
    if (i < 65536) ws[57344 + i] = f2bf(wv1f[i]);
}

// ---- plane transpose: [6][32][256][256] f32 -> [6][256][256][32] ----
__global__ __launch_bounds__(256) void transpose_planes_f32(const float* __restrict__ planes,
                                                            float* __restrict__ trf) {
    __shared__ float lds[64][34];
    const int b = blockIdx.x;              // 0..6143
    const int pl6 = b >> 10;
    const int rem = b & 1023;
    const int y = rem >> 2;
    const int x0 = (rem & 3) << 6;
    const int t = threadIdx.x;
    const float* src = planes + ((size_t)pl6 << 21) + y * 256 + x0;
    #pragma unroll
    for (int it = 0; it < 8; ++it) {
        const int idx = t + it * 256;
        const int c = idx >> 6, x = idx & 63;
        lds[x][c] = src[((size_t)c << 16) + x];
    }
    __syncthreads();
    float* dst = trf + ((((size_t)pl6 << 16) + (y << 8) + x0) << 5);
    float4 v0, v1;
    const int x = t >> 2, c0 = (t & 3) << 3;
    v0.x = lds[x][c0];     v0.y = lds[x][c0 + 1]; v0.z = lds[x][c0 + 2]; v0.w = lds[x][c0 + 3];
    v1.x = lds[x][c0 + 4]; v1.y = lds[x][c0 + 5]; v1.z = lds[x][c0 + 6]; v1.w = lds[x][c0 + 7];
    *reinterpret_cast<float4*>(dst + t * 8)     = v0;
    *reinterpret_cast<float4*>(dst + t * 8 + 4) = v1;
}

__global__ __launch_bounds__(256) void transpose_planes_bf16(const float* __restrict__ planes,
                                                             unsigned short* __restrict__ tr) {
    __shared__ float lds[64][34];
    const int b = blockIdx.x;
    const int pl6 = b >> 10;
    const int rem = b & 1023;
    const int y = rem >> 2;
    const int x0 = (rem & 3) << 6;
    const int t = threadIdx.x;
    const float* src = planes + ((size_t)pl6 << 21) + y * 256 + x0;
    #pragma unroll
    for (int it = 0; it < 8; ++it) {
        const int idx = t + it * 256;
        const int c = idx >> 6, x = idx & 63;
        lds[x][c] = src[((size_t)c << 16) + x];
    }
    __syncthreads();
    unsigned short* dst = tr + ((((size_t)pl6 << 16) + (y << 8) + x0) << 5);
    const int x = t >> 2, c0 = (t & 3) << 3;
    u16x8 v;
    #pragma unroll
    for (int j = 0; j < 8; ++j) v[j] = f2bf(lds[x][c0 + j]);
    *reinterpret_cast<u16x8*>(dst + t * 8) = v;
}

__global__ __launch_bounds__(256) void triplane_mfma(
    const float* __restrict__ planes, const float* __restrict__ pts,
    const float* __restrict__ rays_d, const float* __restrict__ viewdirs,
    const float* __restrict__ z_vals, const float* __restrict__ nearp,
    const float* __restrict__ farp,
    const float* __restrict__ b_sig0, const float* __restrict__ w_sig1,
    const float* __restrict__ b_sig1, const float* __restrict__ b_v0,
    const float* __restrict__ b_v1,  const float* __restrict__ w_rgb,
    const float* __restrict__ b_rgb, const float* __restrict__ betap,
    const unsigned short* __restrict__ wbf, const float* __restrict__ trpf,
    const unsigned short* __restrict__ trp, float* __restrict__ out)
{
    const int tid  = threadIdx.x;
    const int lane = tid & 63;
    const int wv   = tid >> 6;      // wave 0..3 owns cols [wv*64, wv*64+64)
    const int grp  = lane >> 4;     // 16-lane group 0..3
    const int l15  = lane & 15;
    const int ray0 = blockIdx.x * 2;
    const int bat  = ray0 >> 12;    // batch (4096 rays each)

    __shared__ __align__(16) unsigned short samp_lds[48 * 128]; // [row][k] bf16, swizzled
    __shared__ __align__(16) unsigned short h2_lds[48 * 256];   // [row][n] bf16, swizzled (reused for F)
    // overlay into h2_lds (dead until v0 epilogue):
    //   offs  [0,2304)   uint4 per (row,pl): 4 corner element-offsets (abs)  | slow mode: float4 cinfo
    //   wts4  [2304,4608) float4 per (row,pl): 4 masked corner weights
    //   denc  [4608,4736) 2x32 bf16 viewdir encodings
    char* sbase = (char*)h2_lds;
    uint4*  offs  = reinterpret_cast<uint4*>(sbase);
    float4* wts4  = reinterpret_cast<float4*>(sbase + 2304);
    float4* cinfo = reinterpret_cast<float4*>(sbase);           // slow-mode alias
    unsigned short* denc = reinterpret_cast<unsigned short*>(sbase + 4608);

    __shared__ float sdf_part[4][48];
    __shared__ float sdfl[48];
    __shared__ float wtsl[48];
    __shared__ float rgbp[48][3];

    const float nearv  = nearp[0];
    const float inv_fn = 2.0f / (farp[0] - nearv);
    const bool fast = (trpf != nullptr) | (trp != nullptr);

    // ---------- phase 0: per-(row,plane) corner offsets+weights; viewdir encoding ----------
    if (tid < 144) {
        const int row = tid / 3, pl = tid - 3 * (tid / 3);
        const float* pp = pts + (ray0 * NPP + row) * 3;
        float cx, cy;
        if (pl == 0)      { cx = pp[0]; cy = pp[1]; }
        else if (pl == 1) { cx = pp[0]; cy = pp[2]; }
        else              { cx = pp[1]; cy = pp[2]; }
        cx = (cx - nearv) * inv_fn - 1.0f;
        cy = (cy - nearv) * inv_fn - 1.0f;
        const float fx = ((cx + 1.0f) * 256.0f - 1.0f) * 0.5f;
        const float fy = ((cy + 1.0f) * 256.0f - 1.0f) * 0.5f;
        const float fx0 = floorf(fx), fy0 = floorf(fy);
        const int x0 = (int)fx0, y0 = (int)fy0;
        const float wx = fx - fx0, wy = fy - fy0;
        if (fast) {
            const bool vx0 = (x0 >= 0) & (x0 < RES), vx1 = (x0 + 1 >= 0) & (x0 + 1 < RES);
            const bool vy0 = (y0 >= 0) & (y0 < RES), vy1 = (y0 + 1 >= 0) & (y0 + 1 < RES);
            const int xc0 = min(max(x0, 0), RES - 1), xc1 = min(max(x0 + 1, 0), RES - 1);
            const int yc0 = min(max(y0, 0), RES - 1), yc1 = min(max(y0 + 1, 0), RES - 1);
            const unsigned base = (unsigned)(bat * 3 + pl) << 21;
            offs[tid] = make_uint4(base + (((yc0 << 8) + xc0) << 5),
                                   base + (((yc0 << 8) + xc1) << 5),
                                   base + (((yc1 << 8) + xc0) << 5),
                                   base + (((yc1 << 8) + xc1) << 5));
            wts4[tid] = make_float4((vx0 & vy0) ? (1.0f - wx) * (1.0f - wy) : 0.0f,
                                    (vx1 & vy0) ? wx * (1.0f - wy) : 0.0f,
                                    (vx0 & vy1) ? (1.0f - wx) * wy : 0.0f,
                                    (vx1 & vy1) ? wx * wy : 0.0f);
        } else {
            cinfo[tid] = make_float4(fx0, fy0, wx, wy);
        }
    }
    if (tid >= 192) {
        const int j64 = tid - 192;
        const int r = j64 >> 5, j = j64 & 31;
        float v = 0.0f;
        if (j < VD) {
            const float* vd = viewdirs + (ray0 + r) * 3;
            if (j < 3) v = vd[j];
            else if (j < 15) { int k = (j - 3) / 3, c = (j - 3) % 3;
                v = __sinf((float)(1 << k) * 3.14159265358979323846f * vd[c]); }
            else { int k = (j - 15) / 3, c = (j - 15) % 3;
                v = __cosf((float)(1 << k) * 3.14159265358979323846f * vd[c]); }
        }
        denc[r * 32 + j] = f2bf(v);
    }
    __syncthreads();

    // ---------- phase 1: bilinear gather (48 rows x 96 ch) ----------
    if (trpf) {
        // f32 channel-last: unit = (row,pl, 8-ch group)
        #pragma unroll
        for (int it = 0; it < 3; ++it) {
            const int u = tid + it * 256;
            if (u < 576) {
                const int pp = u >> 2, c8 = (u & 3) << 3;
                const int row = pp / 3, pl = pp - 3 * (pp / 3);
                const uint4  o = offs[pp];
                const float4 w = wts4[pp];
                const float4 a0 = *reinterpret_cast<const float4*>(trpf + o.x + c8);
                const float4 a1 = *reinterpret_cast<const float4*>(trpf + o.x + c8 + 4);
                const float4 b0 = *reinterpret_cast<const float4*>(trpf + o.y + c8);
                const float4 b1 = *reinterpret_cast<const float4*>(trpf + o.y + c8 + 4);
                const float4 c0 = *reinterpret_cast<const float4*>(trpf + o.z + c8);
                const float4 c1 = *reinterpret_cast<const float4*>(trpf + o.z + c8 + 4);
                const float4 d0 = *reinterpret_cast<const float4*>(trpf + o.w + c8);
                const float4 d1 = *reinterpret_cast<const float4*>(trpf + o.w + c8 + 4);
                const float r0 = a0.x * w.x + b0.x * w.y + c0.x * w.z + d0.x * w.w;
                const float r1 = a0.y * w.x + b0.y * w.y + c0.y * w.z + d0.y * w.w;
                const float r2 = a0.z * w.x + b0.z * w.y + c0.z * w.z + d0.z * w.w;
                const float r3 = a0.w * w.x + b0.w * w.y + c0.w * w.z + d0.w * w.w;
                const float r4 = a1.x * w.x + b1.x * w.y + c1.x * w.z + d1.x * w.w;
                const float r5 = a1.y * w.x + b1.y * w.y + c1.y * w.z + d1.y * w.w;
                const float r6 = a1.z * w.x + b1.z * w.y + c1.z * w.z + d1.z * w.w;
                const float r7 = a1.w * w.x + b1.w * w.y + c1.w * w.z + d1.w * w.w;
                uint4 pk;
                pk.x = cvtpk(r0, r1); pk.y = cvtpk(r2, r3);
                pk.z = cvtpk(r4, r5); pk.w = cvtpk(r6, r7);
                *reinterpret_cast<uint4*>(samp_lds + swzA(row, pl * 32 + c8)) = pk;
            }
        }
    } else if (trp) {
        // bf16 channel-last fallback
        #pragma unroll
        for (int it = 0; it < 3; ++it) {
            const int u = tid + it * 256;
            if (u < 576) {
                const int pp = u >> 2, c8 = (u & 3) << 3;
                const int row = pp / 3, pl = pp - 3 * (pp / 3);
                const uint4  o = offs[pp];
                const float4 w = wts4[pp];
                const u16x8 v00 = *reinterpret_cast<const u16x8*>(trp + o.x + c8);
                const u16x8 v10 = *reinterpret_cast<const u16x8*>(trp + o.y + c8);
                const u16x8 v01 = *reinterpret_cast<const u16x8*>(trp + o.z + c8);
                const u16x8 v11 = *reinterpret_cast<const u16x8*>(trp + o.w + c8);
                float r[8];
                #pragma unroll
                for (int j = 0; j < 8; ++j)
                    r[j] = bf2f(v00[j]) * w.x + bf2f(v10[j]) * w.y
                         + bf2f(v01[j]) * w.z + bf2f(v11[j]) * w.w;
                uint4 pk;
                pk.x = cvtpk(r[0], r[1]); pk.y = cvtpk(r[2], r[3]);
                pk.z = cvtpk(r[4], r[5]); pk.w = cvtpk(r[6], r[7]);
                *reinterpret_cast<uint4*>(samp_lds + swzA(row, pl * 32 + c8)) = pk;
            }
        }
    } else {
        // slow path: channel-major f32
        #pragma unroll
        for (int it = 0; it < 18; ++it) {
            const int s = tid + it * 256;
            const int row = s / 96, j = s - row * 96;
            const int pl = j >> 5, c = j & 31;
            const float4 ci = cinfo[row * 3 + pl];
            const int x0 = (int)ci.x, y0 = (int)ci.y;
            const float wx = ci.z, wy = ci.w;
            const float* base = planes + (((size_t)((bat * 3 + pl) * 32 + c)) << 16);
            float acc = 0.0f;
            #pragma unroll
            for (int dy = 0; dy < 2; ++dy)
            #pragma unroll
            for (int dx = 0; dx < 2; ++dx) {
                const int ix = x0 + dx, iy = y0 + dy;
                const bool valid = (ix >= 0) & (ix < RES) & (iy >= 0) & (iy < RES);
                const int cix = min(max(ix, 0), RES - 1);
                const int ciy = min(max(iy, 0), RES - 1);
                const float w = (dx ? wx : 1.0f - wx) * (dy ? wy : 1.0f - wy);
                acc += base[ciy * RES + cix] * (valid ? w : 0.0f);
            }
            samp_lds[swzA(row, j)] = f2bf(acc);
        }
    }
    #pragma unroll
    for (int it = 0; it < 6; ++it) {
        const int s = tid + it * 256;          // 0..1535
        const int row = s >> 5, j = s & 31;
        samp_lds[swzA(row, 96 + j)] = denc[(row >= 24) * 32 + j];  // cols 96..122 denc, rest 0
    }
    __syncthreads();

    const unsigned short* ws0 = wbf;
    const unsigned short* wv0w = wbf + 24576;
    const unsigned short* wv1w = wbf + 57344;
    const f32x4 fzero = {0.0f, 0.0f, 0.0f, 0.0f};

    f32x4 acc[3][4];

    // ---------- sig0: H[48x256] = samp[48x96] @ Wsig0^T ----------
    #pragma unroll
    for (int mt = 0; mt < 3; ++mt)
        #pragma unroll
        for (int nt = 0; nt < 4; ++nt) acc[mt][nt] = fzero;
    #pragma unroll
    for (int ks = 0; ks < 3; ++ks) {
        bf16x8 a[3];
        #pragma unroll
        for (int mt = 0; mt < 3; ++mt)
            a[mt] = *(const bf16x8*)(samp_lds + swzA(mt * 16 + l15, ks * 32 + 8 * grp));
        #pragma unroll
        for (int nt = 0; nt < 4; ++nt) {
            const int n = wv * 64 + nt * 16 + l15;
            const bf16x8 b = *(const bf16x8*)(ws0 + n * 96 + ks * 32 + 8 * grp);
            #pragma unroll
            for (int mt = 0; mt < 3; ++mt)
                acc[mt][nt] = __builtin_amdgcn_mfma_f32_16x16x32_bf16(a[mt], b, acc[mt][nt], 0, 0, 0);
        }
    }
    // sdf partials: lane holds (row = mt*16+4*grp+r, col = wv*64+nt*16+l15)
    {
        float b0c[4], w1c[4];
        #pragma unroll
        for (int nt = 0; nt < 4; ++nt) {
            const int col = wv * 64 + nt * 16 + l15;
            b0c[nt] = b_sig0[col]; w1c[nt] = w_sig1[col];
        }
        #pragma unroll
        for (int mt = 0; mt < 3; ++mt)
        #pragma unroll
        for (int r = 0; r < 4; ++r) {
            float s = 0.0f;
            #pragma unroll
            for (int nt = 0; nt < 4; ++nt)
                s += softplusf(acc[mt][nt][r] + b0c[nt]) * w1c[nt];
            s += __shfl_xor(s, 1, 64); s += __shfl_xor(s, 2, 64);
            s += __shfl_xor(s, 4, 64); s += __shfl_xor(s, 8, 64);
            if (l15 == 0) sdf_part[wv][mt * 16 + 4 * grp + r] = s;
        }
    }
    __syncthreads();
    if (tid < 48) {
        const float s = sdf_part[0][tid] + sdf_part[1][tid] + sdf_part[2][tid]
                      + sdf_part[3][tid] + b_sig1[0];
        sdfl[tid] = s;
        out[SDF_OFF + ray0 * NPP + tid] = s;
    }
    __syncthreads();
    // render weights (serial N=24, one thread per ray) — overlaps v0 MFMA
    if (tid < 2) {
        const int ray = ray0 + tid;
        const float dx = rays_d[ray * 3], dy = rays_d[ray * 3 + 1], dz = rays_d[ray * 3 + 2];
        const float nrm = sqrtf(dx * dx + dy * dy + dz * dz);
        const float beta = betap[0];
        float T = 1.0f;
        #pragma unroll
        for (int p = 0; p < NPP; ++p) {
            const float dist = ((p < NPP - 1) ? (z_vals[ray * NPP + p + 1] - z_vals[ray * NPP + p])
                                              : 1.0e10f) * nrm;
            const float sg = sigmoidf_(-sdfl[tid * NPP + p] / beta) / beta;
            const float alpha = 1.0f - expf(-sg * dist);
            wtsl[tid * NPP + p] = alpha * T;
            T *= (1.0f - alpha + 1e-10f);
        }
        out[MASK_OFF + ray] = wtsl[tid * NPP + NPP - 1];
    }

    // ---------- v0: H2[48x256] = [samp|denc][48x128] @ Wv0pad^T ----------
    #pragma unroll
    for (int mt = 0; mt < 3; ++mt)
        #pragma unroll
        for (int nt = 0; nt < 4; ++nt) acc[mt][nt] = fzero;
    #pragma unroll
    for (int ks = 0; ks < 4; ++ks) {
        bf16x8 a[3];
        #pragma unroll
        for (int mt = 0; mt < 3; ++mt)
            a[mt] = *(const bf16x8*)(samp_lds + swzA(mt * 16 + l15, ks * 32 + 8 * grp));
        #pragma unroll
        for (int nt = 0; nt < 4; ++nt) {
            const int n = wv * 64 + nt * 16 + l15;
            const bf16x8 b = *(const bf16x8*)(wv0w + n * 128 + ks * 32 + 8 * grp);
            #pragma unroll
            for (int mt = 0; mt < 3; ++mt)
                acc[mt][nt] = __builtin_amdgcn_mfma_f32_16x16x32_bf16(a[mt], b, acc[mt][nt], 0, 0, 0);
        }
    }
    // NOTE: h2_lds writes below clobber offs/wts/denc overlay (dead now)
    #pragma unroll
    for (int nt = 0; nt < 4; ++nt) {
        const int col = wv * 64 + nt * 16 + l15;
        const float bv = b_v0[col];
        #pragma unroll
        for (int mt = 0; mt < 3; ++mt) {
            const int r0 = mt * 16 + 4 * grp;
            const float s0 = softplusf(acc[mt][nt][0] + bv);
            const float s1 = softplusf(acc[mt][nt][1] + bv);
            const float s2 = softplusf(acc[mt][nt][2] + bv);
            const float s3 = softplusf(acc[mt][nt][3] + bv);
            const unsigned q0 = cvtpk(s0, s1), q1 = cvtpk(s2, s3);
            h2_lds[swzH(r0,     col)] = (unsigned short)q0;
            h2_lds[swzH(r0 + 1, col)] = (unsigned short)(q0 >> 16);
            h2_lds[swzH(r0 + 2, col)] = (unsigned short)q1;
            h2_lds[swzH(r0 + 3, col)] = (unsigned short)(q1 >> 16);
        }
    }
    __syncthreads();   // h2 complete + wtsl complete
    if (tid < 6) {
        const int rr = tid / 3, c = tid - rr * 3;
        float a = 0.0f;
        #pragma unroll
        for (int p = 0; p < NPP; ++p)
            a += wtsl[rr * NPP + p] * pts[(ray0 * NPP + rr * NPP + p) * 3 + c];
        out[XYZ_OFF + (ray0 + rr) * 3 + c] = a;
    }

    // ---------- v1: F[48x256] = H2[48x256] @ Wv1^T ----------
    #pragma unroll
    for (int mt = 0; mt < 3; ++mt)
        #pragma unroll
        for (int nt = 0; nt < 4; ++nt) acc[mt][nt] = fzero;
    #pragma unroll
    for (int ks = 0; ks < 8; ++ks) {
        bf16x8 a[3];
        #pragma unroll
        for (int mt = 0; mt < 3; ++mt)
            a[mt] = *(const bf16x8*)(h2_lds + swzH(mt * 16 + l15, ks * 32 + 8 * grp));
        #pragma unroll
        for (int nt = 0; nt < 4; ++nt) {
            const int n = wv * 64 + nt * 16 + l15;
            const bf16x8 b = *(const bf16x8*)(wv1w + n * 256 + ks * 32 + 8 * grp);
            #pragma unroll
            for (int mt = 0; mt < 3; ++mt)
                acc[mt][nt] = __builtin_amdgcn_mfma_f32_16x16x32_bf16(a[mt], b, acc[mt][nt], 0, 0, 0);
        }
    }
    __syncthreads();   // all v1 reads of h2_lds done before overwrite with F

    // F = acc + b_v1; feature_map (f32) + store F bf16 for rgb
    {
        float wr[12];
        #pragma unroll
        for (int mt = 0; mt < 3; ++mt)
            #pragma unroll
            for (int r = 0; r < 4; ++r) wr[mt * 4 + r] = wtsl[mt * 16 + 4 * grp + r];
        #pragma unroll
        for (int nt = 0; nt < 4; ++nt) {
            const int col = wv * 64 + nt * 16 + l15;
            const float bv = b_v1[col];
            float fm0 = 0.0f, fm1 = 0.0f;
            #pragma unroll
            for (int mt = 0; mt < 3; ++mt) {
                const int r0 = mt * 16 + 4 * grp;
                float F[4];
                #pragma unroll
                for (int r = 0; r < 4; ++r) {
                    F[r] = acc[mt][nt][r] + bv;
                    const float wf = wr[mt * 4 + r] * F[r];
                    if (r0 + r < NPP) fm0 += wf; else fm1 += wf;
                }
                const unsigned q0 = cvtpk(F[0], F[1]), q1 = cvtpk(F[2], F[3]);
                h2_lds[swzH(r0,     col)] = (unsigned short)q0;
                h2_lds[swzH(r0 + 1, col)] = (unsigned short)(q0 >> 16);
                h2_lds[swzH(r0 + 2, col)] = (unsigned short)q1;
                h2_lds[swzH(r0 + 3, col)] = (unsigned short)(q1 >> 16);
            }
            fm0 += __shfl_xor(fm0, 16, 64); fm0 += __shfl_xor(fm0, 32, 64);
            fm1 += __shfl_xor(fm1, 16, 64); fm1 += __shfl_xor(fm1, 32, 64);
            if (grp == 0) {
                out[FEAT_OFF + ray0 * WH + col] = fm0;
                out[FEAT_OFF + (ray0 + 1) * WH + col] = fm1;
            }
        }
    }
    __syncthreads();

    // ---------- rgb: rgb[p][c] = sigmoid(F[p] . w_rgb[c] + b_rgb[c]) ----------
    if (tid < 144) {
        const int c = tid / 48, p = tid - c * 48;
        float accr = 0.0f;
        #pragma unroll
        for (int j = 0; j < 32; ++j) {
            const bf16x8 v = *(const bf16x8*)(h2_lds + swzH(p, 8 * j));
            const float4 w0 = *(const float4*)(w_rgb + c * WH + 8 * j);
            const float4 w1 = *(const float4*)(w_rgb + c * WH + 8 * j + 4);
            accr += bf2f((unsigned short)v[0]) * w0.x + bf2f((unsigned short)v[1]) * w0.y
                  + bf2f((unsigned short)v[2]) * w0.z + bf2f((unsigned short)v[3]) * w0.w
                  + bf2f((unsigned short)v[4]) * w1.x + bf2f((unsigned short)v[5]) * w1.y
                  + bf2f((unsigned short)v[6]) * w1.z + bf2f((unsigned short)v[7]) * w1.w;
        }
        rgbp[p][c] = wtsl[p] * sigmoidf_(accr + b_rgb[c]);
    }
    __syncthreads();
    if (tid < 6) {
        const int rr = tid / 3, c = tid - rr * 3;
        float s = 0.0f;
        #pragma unroll
        for (int p = 0; p < NPP; ++p) s += rgbp[rr * NPP + p][c];
        out[RGB_OFF + (ray0 + rr) * 3 + c] = -1.0f + 2.0f * s;
    }
}

extern "C" void kernel_launch(void* const* d_in, const int* in_sizes, int n_in,
                              void* d_out, int out_size, void* d_ws, size_t ws_size,
                              hipStream_t stream) {
    const float* planes   = (const float*)d_in[0];
    const float* pts      = (const float*)d_in[1];
    const float* rays_d   = (const float*)d_in[2];
    const float* viewdirs = (const float*)d_in[3];
    const float* z_vals   = (const float*)d_in[4];
    const float* nearp    = (const float*)d_in[5];
    const float* farp     = (const float*)d_in[6];
    const float* w_sig0   = (const float*)d_in[7];
    const float* b_sig0   = (const float*)d_in[8];
    const float* w_sig1   = (const float*)d_in[9];
    const float* b_sig1   = (const float*)d_in[10];
    const float* w_v0     = (const float*)d_in[11];
    const float* b_v0     = (const float*)d_in[12];
    const float* w_v1     = (const float*)d_in[13];
    const float* b_v1     = (const float*)d_in[14];
    const float* w_rgb    = (const float*)d_in[15];
    const float* b_rgb    = (const float*)d_in[16];
    const float* betap    = (const float*)d_in[17];
    float* out = (float*)d_out;
    unsigned short* wbf = (unsigned short*)d_ws;        // 245,760 B weights @0

    const size_t TR_OFF_B = 262144;                     // 256 KB aligned
    const size_t TRF_BYTES = (size_t)6 * 256 * 256 * 32 * 4;  // 48 MB f32
    const float* trpf = nullptr;
    const unsigned short* trp = nullptr;
    if (ws_size >= TR_OFF_B + TRF_BYTES) {
        float* t = (float*)((char*)d_ws + TR_OFF_B);
        transpose_planes_f32<<<6144, 256, 0, stream>>>(planes, t);
        trpf = t;
    } else if (ws_size >= TR_OFF_B + TRF_BYTES / 2) {
        unsigned short* t = (unsigned short*)((char*)d_ws + TR_OFF_B);
        transpose_planes_bf16<<<6144, 256, 0, stream>>>(planes, t);
        trp = t;
    }
    conv_weights<<<256, 256, 0, stream>>>(w_sig0, w_v0, w_v1, wbf);
    triplane_mfma<<<4096, 256, 0, stream>>>(
        planes, pts, rays_d, viewdirs, z_vals, nearp, farp,
        b_sig0, w_sig1, b_sig1, b_v0, b_v1, w_rgb, b_rgb, betap, wbf, trpf, trp, out);
}